// Round 19
// baseline (657.566 us; speedup 1.0000x reference)
//
#include <hip/hip_runtime.h>

#define NN 50000
#define NE 400000
#define HD 128
#define ND 64
#define GG 16
#define EPSV 1e-5f
#define ETILE 64

#define SLEN (2 * GG * HD + GG)   // 4112 floats: [sum 2048 | sumsq 2048 | cnt 16]
#define PSTRIDE 4352              // partial-set stride (floats), non-pow2
#define ASB 512                   // fused aggr+stats blocks (8 waves each)

typedef unsigned short u16;
typedef unsigned int   u32;
typedef unsigned char  u8;
typedef __attribute__((__ext_vector_type__(8))) __bf16 bf16x8;
typedef __attribute__((__ext_vector_type__(4))) float  f32x4;

__device__ __forceinline__ float us2f(u16 u) { return __uint_as_float(((u32)u) << 16); }
__device__ __forceinline__ u16 f2us(float f) {
    u32 u = __float_as_uint(f);
    u += 0x7fffu + ((u >> 16) & 1u);   // RNE
    return (u16)(u >> 16);
}
__device__ __forceinline__ float sigmoidf_(float x) { return 1.f / (1.f + __expf(-x)); }

// ---------------------------------------------------------------------------
// K0a: Wep = We @ Wp  [64x128], bep = be @ Wp + bp   (grid=16, Wp in LDS)
// ---------------------------------------------------------------------------
__global__ __launch_bounds__(256) void wep_kernel(
    const float* __restrict__ We, const float* __restrict__ Wp,
    const float* __restrict__ be, const float* __restrict__ bp,
    float* __restrict__ Wep, float* __restrict__ bep)
{
    __shared__ float wp[HD][HD];      // 64 KB
    const int t = threadIdx.x;
    for (int i = t; i < HD * HD; i += 256) wp[i >> 7][i & 127] = Wp[i];
    __syncthreads();
    const int c = t & 127;
    for (int r = blockIdx.x * 4 + (t >> 7); r < (blockIdx.x + 1) * 4 && r < ND; r += 2) {
        float a = 0.f;
        for (int k = 0; k < HD; ++k) a = fmaf(We[r * HD + k], wp[k][c], a);
        Wep[r * HD + c] = a;
    }
    if (blockIdx.x == 0 && t < HD) {
        float a = bp[t];
        for (int k = 0; k < HD; ++k) a = fmaf(be[k], wp[k][t], a);
        bep[t] = a;
    }
}

// ---------------------------------------------------------------------------
// K0e: all weight transposes in ONE launch. grid=(64,7).
// ---------------------------------------------------------------------------
__global__ __launch_bounds__(256) void prep_all_kernel(
    const float* __restrict__ Wq, const float* __restrict__ Wr,
    const float* __restrict__ Wv, const float* __restrict__ Wu,
    const float* __restrict__ Wo, const float* __restrict__ Wep,
    const float* __restrict__ We,
    u16* __restrict__ WqT, u16* __restrict__ WrT, u16* __restrict__ WvT,
    u16* __restrict__ WuT, u16* __restrict__ WoT, u16* __restrict__ WepT,
    u16* __restrict__ WeT)
{
    const float* in; u16* out; int K;
    switch (blockIdx.y) {
        case 0: in = Wq;  out = WqT;  K = HD; break;
        case 1: in = Wr;  out = WrT;  K = HD; break;
        case 2: in = Wv;  out = WvT;  K = HD; break;
        case 3: in = Wu;  out = WuT;  K = HD; break;
        case 4: in = Wo;  out = WoT;  K = HD; break;
        case 5: in = Wep; out = WepT; K = ND; break;
        default: in = We; out = WeT;  K = ND; break;
    }
    int idx = blockIdx.x * 256 + threadIdx.x;
    if (idx >= K * HD) return;
    int k = idx >> 7, n = idx & 127;
    out[n * K + k] = f2us(in[idx]);
}

// ---------------------------------------------------------------------------
// K0b: degree histogram
// ---------------------------------------------------------------------------
__global__ __launch_bounds__(256) void hist_kernel(
    const int* __restrict__ srcArr, u32* __restrict__ deg)
{
    int e = blockIdx.x * 256 + threadIdx.x;
    if (e >= NE) return;
    atomicAdd(&deg[srcArr[e]], 1u);
}

// ---------------------------------------------------------------------------
// K0c: exclusive prefix sum of deg[NN] -> start[NN+1]   (1 block, 1024 thr)
// ---------------------------------------------------------------------------
#define SCAN_C 49   // 1024*49 = 50176 >= NN
__global__ __launch_bounds__(1024) void scan_kernel(
    const u32* __restrict__ deg, int* __restrict__ start)
{
    __shared__ u32 sums[1024];
    const int t = threadIdx.x;
    const int i0 = t * SCAN_C;
    u32 tot = 0;
    for (int j = 0; j < SCAN_C; ++j) { int i = i0 + j; if (i < NN) tot += deg[i]; }
    sums[t] = tot;
    __syncthreads();
    for (int off = 1; off < 1024; off <<= 1) {
        u32 v = (t >= off) ? sums[t - off] : 0u;
        __syncthreads();
        sums[t] += v;
        __syncthreads();
    }
    u32 run = (t == 0) ? 0u : sums[t - 1];
    for (int j = 0; j < SCAN_C; ++j) {
        int i = i0 + j;
        if (i < NN) { start[i] = (int)run; run += deg[i]; }
    }
    if (t == 1023) start[NN] = (int)run;   // == NE
}

// ---------------------------------------------------------------------------
// K0d: scatter edges into CSR order + dst/g8 in CSR order + iperm[e] = j
// ---------------------------------------------------------------------------
__global__ __launch_bounds__(256) void scatter_kernel(
    const int* __restrict__ srcArr, const int* __restrict__ dstArr,
    const int* __restrict__ batch, const int* __restrict__ start,
    u32* __restrict__ cnt2, int* __restrict__ perm,
    int* __restrict__ iperm, int* __restrict__ dst_csr,
    u8* __restrict__ g8csr)
{
    int e = blockIdx.x * 256 + threadIdx.x;
    if (e >= NE) return;
    int s = srcArr[e];
    u32 pos = atomicAdd(&cnt2[s], 1u);
    int j = start[s] + (int)pos;
    perm[j] = e;
    iperm[e] = j;
    dst_csr[j] = dstArr[e];
    g8csr[j] = (u8)batch[s];
}

// ---------------------------------------------------------------------------
// K1: MFMA: fq/fr/fv = feat @ {Wq,Wr,Wv} + b (bf16); fu32 = feat@Wu + bu (f32)
//     Weights staged per-matrix in LDS fragment order (32 KB).
// ---------------------------------------------------------------------------
__global__ __launch_bounds__(256) void proj4_kernel(
    const float* __restrict__ feat,
    const u16* __restrict__ WqT, const u16* __restrict__ WrT,
    const u16* __restrict__ WvT, const u16* __restrict__ WuT,
    const float* __restrict__ bq, const float* __restrict__ br,
    const float* __restrict__ bv, const float* __restrict__ bu,
    u16* __restrict__ fq, u16* __restrict__ fr, u16* __restrict__ fv,
    float* __restrict__ fu32)
{
    __shared__ __align__(16) u16 As[ETILE * HD];   // 16 KB, XOR-swizzled
    __shared__ __align__(16) u16 WL[2048 * 8];     // 32 KB, fragment order
    const int t = threadIdx.x;
    const int rbase = blockIdx.x * ETILE;
    #pragma unroll
    for (int i = 0; i < 16; ++i) {
        int idx2 = t + i * 256;            // bf16-pair index
        int row = idx2 >> 6, p = idx2 & 63;
        int grow = rbase + row;
        float2 v = make_float2(0.f, 0.f);
        if (grow < NN) v = *reinterpret_cast<const float2*>(&feat[(size_t)grow * HD + p * 2]);
        u32 pk = (u32)f2us(v.x) | ((u32)f2us(v.y) << 16);
        int off = (row * 256 + p * 4) ^ ((row & 7) << 4);
        *reinterpret_cast<u32*>(reinterpret_cast<char*>(As) + off) = pk;
    }
    __syncthreads();
    const int w = t >> 6, lane = t & 63;
    const int rt = w * 16, l15 = lane & 15, kg = lane >> 4;
    const int lrow = rt + l15;
    bf16x8 afr[4];
    #pragma unroll
    for (int kk = 0; kk < 4; ++kk) {
        int off = (lrow * 256 + (kk * 32 + kg * 8) * 2) ^ ((lrow & 7) << 4);
        afr[kk] = *reinterpret_cast<const bf16x8*>(reinterpret_cast<const char*>(As) + off);
    }
    const u16* WTs[4] = {WqT, WrT, WvT, WuT};
    const float* Bs2[4] = {bq, br, bv, bu};
    u16* Os[3] = {fq, fr, fv};
    const int lid = kg * 16 + l15;
    #pragma unroll
    for (int m = 0; m < 4; ++m) {
        const u16* W = WTs[m];
        #pragma unroll
        for (int q = 0; q < 8; ++q) {
            int f = t + q * 256;
            int fl15 = f & 15, kgi = (f >> 4) & 15, fnt = f >> 8;
            *reinterpret_cast<uint4*>(&WL[f * 8]) =
                *reinterpret_cast<const uint4*>(&W[(size_t)(fnt * 16 + fl15) * HD + kgi * 8]);
        }
        __syncthreads();
        f32x4 acc[8];
        #pragma unroll
        for (int nt = 0; nt < 8; ++nt) { acc[nt][0]=0.f; acc[nt][1]=0.f; acc[nt][2]=0.f; acc[nt][3]=0.f; }
        #pragma unroll
        for (int nt = 0; nt < 8; ++nt) {
            #pragma unroll
            for (int kk = 0; kk < 4; ++kk) {
                bf16x8 b = *reinterpret_cast<const bf16x8*>(&WL[(((nt * 4 + kk) * 64) + lid) * 8]);
                acc[nt] = __builtin_amdgcn_mfma_f32_16x16x32_bf16(afr[kk], b, acc[nt], 0, 0, 0);
            }
        }
        #pragma unroll
        for (int nt = 0; nt < 8; ++nt) {
            int gcol = nt * 16 + l15;
            float bias = Bs2[m][gcol];
            #pragma unroll
            for (int i = 0; i < 4; ++i) {
                int grow = rbase + rt + kg * 4 + i;
                if (grow < NN) {
                    float v = acc[nt][i] + bias;
                    if (m < 3) Os[m][(size_t)grow * HD + gcol] = f2us(v);
                    else       fu32[(size_t)grow * HD + gcol] = v;
                }
            }
        }
        __syncthreads();   // all reads of WL done before next-stage overwrite
    }
}

// ---------------------------------------------------------------------------
// K3: MFMA in ORIGINAL edge order: for edge e,
//   ehat_csr[iperm[e]] = noise[e]@Wep + bep + fq[srcArr[e]] + fr[dstArr[e]]
// ---------------------------------------------------------------------------
__global__ __launch_bounds__(256) void ehat_kernel(
    const float* __restrict__ noise, const u16* __restrict__ WepT,
    const float* __restrict__ bep,
    const u16* __restrict__ fq, const u16* __restrict__ fr,
    const int* __restrict__ srcArr, const int* __restrict__ dstArr,
    const int* __restrict__ iperm,
    u16* __restrict__ ehat_csr)
{
    __shared__ __align__(16) u16 WeL[1024 * 8];   // 16 KB, fragment order
    const int t = threadIdx.x;
    #pragma unroll
    for (int q = 0; q < 4; ++q) {
        int f = t + q * 256;
        int fl15 = f & 15, kgi = (f >> 4) & 7, fnt = f >> 7;
        *reinterpret_cast<uint4*>(&WeL[f * 8]) =
            *reinterpret_cast<const uint4*>(&WepT[(size_t)(fnt * 16 + fl15) * ND + kgi * 8]);
    }
    const int rbase = blockIdx.x * ETILE;
    const int w = t >> 6, lane = t & 63;
    const int rt = w * 16, l15 = lane & 15, kg = lane >> 4;
    const int el = rbase + rt + l15;      // original edge (A-frag row) — coalesced
    u32 an[2][4];
    #pragma unroll
    for (int kk = 0; kk < 2; ++kk) {
        const int c = kk * 32 + kg * 8;
        float4 n0 = *reinterpret_cast<const float4*>(&noise[(size_t)el * ND + c]);
        float4 n1 = *reinterpret_cast<const float4*>(&noise[(size_t)el * ND + c + 4]);
        an[kk][0] = (u32)f2us(n0.x) | ((u32)f2us(n0.y) << 16);
        an[kk][1] = (u32)f2us(n0.z) | ((u32)f2us(n0.w) << 16);
        an[kk][2] = (u32)f2us(n1.x) | ((u32)f2us(n1.y) << 16);
        an[kk][3] = (u32)f2us(n1.z) | ((u32)f2us(n1.w) << 16);
    }
    __syncthreads();
    f32x4 acc[8];
    #pragma unroll
    for (int nt = 0; nt < 8; ++nt) {
        float b = bep[nt * 16 + l15];
        acc[nt][0] = b; acc[nt][1] = b; acc[nt][2] = b; acc[nt][3] = b;
    }
    const int lid = kg * 16 + l15;
    #pragma unroll
    for (int nt = 0; nt < 8; ++nt) {
        #pragma unroll
        for (int kk = 0; kk < 2; ++kk) {
            bf16x8 b = *reinterpret_cast<const bf16x8*>(&WeL[(((nt * 2 + kk) * 64) + lid) * 8]);
            acc[nt] = __builtin_amdgcn_mfma_f32_16x16x32_bf16(
                *reinterpret_cast<const bf16x8*>(an[kk]), b, acc[nt], 0, 0, 0);
        }
    }
    #pragma unroll
    for (int i = 0; i < 4; ++i) {
        int e = rbase + rt + kg * 4 + i;
        int s = srcArr[e], d = dstArr[e];
        int j = iperm[e];
        #pragma unroll
        for (int nt = 0; nt < 8; ++nt) {
            int gcol = nt * 16 + l15;
            float v = acc[nt][i]
                    + us2f(fq[(size_t)s * HD + gcol]) + us2f(fr[(size_t)d * HD + gcol]);
            ehat_csr[(size_t)j * HD + gcol] = f2us(v);
        }
    }
}

// ---------------------------------------------------------------------------
// K3b (FUSED): one CSR-sequential pass computing aggregation + e/h stats
// ---------------------------------------------------------------------------
__global__ __launch_bounds__(512) void aggr_stats_kernel(
    const u16* __restrict__ ehat_csr, const u16* __restrict__ fv,
    const int* __restrict__ dst_csr, const int* __restrict__ start,
    const int* __restrict__ batch, float* __restrict__ xout,
    float* __restrict__ part)
{
    __shared__ float sm[2 * SLEN];   // 32.9 KB: [e: sum|sumsq|cnt][h: sum|sumsq|cnt]
    const int t = threadIdx.x;
    for (int i = t; i < 2 * SLEN; i += 512) sm[i] = 0.f;
    __syncthreads();
    const int wid = blockIdx.x * 8 + (t >> 6);
    const int lane = t & 63;
    const int c0 = lane * 2;
    const int NW = ASB * 8;
    const int chunk = (NN + NW - 1) / NW;
    const int n0 = wid * chunk;
    const int n1 = min(NN, n0 + chunk);
    const float inc = (lane == 0) ? 1.f : 0.f;
    float es0=0.f, es1=0.f, ez0=0.f, ez1=0.f, ecn=0.f;
    float hs0=0.f, hs1=0.f, hz0=0.f, hz1=0.f, hcn=0.f;
    int curg = -1;
    for (int node = n0; node < n1; ++node) {
        int g = __builtin_amdgcn_readfirstlane(batch[node]);
        if (g != curg) {
            if (curg >= 0) {
                unsafeAtomicAdd(&sm[curg * HD + c0],            es0);
                unsafeAtomicAdd(&sm[curg * HD + c0 + 1],        es1);
                unsafeAtomicAdd(&sm[2048 + curg * HD + c0],     ez0);
                unsafeAtomicAdd(&sm[2048 + curg * HD + c0 + 1], ez1);
                unsafeAtomicAdd(&sm[SLEN + curg * HD + c0],            hs0);
                unsafeAtomicAdd(&sm[SLEN + curg * HD + c0 + 1],        hs1);
                unsafeAtomicAdd(&sm[SLEN + 2048 + curg * HD + c0],     hz0);
                unsafeAtomicAdd(&sm[SLEN + 2048 + curg * HD + c0 + 1], hz1);
                if (lane == 0) {
                    unsafeAtomicAdd(&sm[4096 + curg], ecn);
                    unsafeAtomicAdd(&sm[SLEN + 4096 + curg], hcn);
                }
                es0=0.f; es1=0.f; ez0=0.f; ez1=0.f; ecn=0.f;
                hs0=0.f; hs1=0.f; hz0=0.f; hz1=0.f; hcn=0.f;
            }
            curg = g;
        }
        int s0 = start[node], s1 = start[node + 1];
        float2 uv = *reinterpret_cast<const float2*>(&xout[(size_t)node * HD + c0]);
        float a0 = 0.f, a1 = 0.f;
        for (int j = s0; j < s1; ++j) {
            int d = dst_csr[j];
            u32 ev = *reinterpret_cast<const u32*>(&ehat_csr[(size_t)j * HD + c0]);
            u32 vv = *reinterpret_cast<const u32*>(&fv[(size_t)d * HD + c0]);
            float x0 = us2f((u16)ev), x1 = us2f((u16)(ev >> 16));
            a0 = fmaf(sigmoidf_(x0), us2f((u16)vv),         a0);
            a1 = fmaf(sigmoidf_(x1), us2f((u16)(vv >> 16)), a1);
            es0 += x0; ez0 = fmaf(x0, x0, ez0);
            es1 += x1; ez1 = fmaf(x1, x1, ez1);
            ecn += inc;
        }
        float xx0 = a0 + uv.x, xx1 = a1 + uv.y;
        *reinterpret_cast<float2*>(&xout[(size_t)node * HD + c0]) = make_float2(xx0, xx1);
        hs0 += xx0; hz0 = fmaf(xx0, xx0, hz0);
        hs1 += xx1; hz1 = fmaf(xx1, xx1, hz1);
        hcn += inc;
    }
    if (curg >= 0) {
        unsafeAtomicAdd(&sm[curg * HD + c0],            es0);
        unsafeAtomicAdd(&sm[curg * HD + c0 + 1],        es1);
        unsafeAtomicAdd(&sm[2048 + curg * HD + c0],     ez0);
        unsafeAtomicAdd(&sm[2048 + curg * HD + c0 + 1], ez1);
        unsafeAtomicAdd(&sm[SLEN + curg * HD + c0],            hs0);
        unsafeAtomicAdd(&sm[SLEN + curg * HD + c0 + 1],        hs1);
        unsafeAtomicAdd(&sm[SLEN + 2048 + curg * HD + c0],     hz0);
        unsafeAtomicAdd(&sm[SLEN + 2048 + curg * HD + c0 + 1], hz1);
        if (lane == 0) {
            unsafeAtomicAdd(&sm[4096 + curg], ecn);
            unsafeAtomicAdd(&sm[SLEN + 4096 + curg], hcn);
        }
    }
    __syncthreads();
    float* dst = part + (size_t)blockIdx.x * (2 * PSTRIDE);
    for (int i = t; i < SLEN; i += 512) {
        dst[i] = sm[i];
        dst[PSTRIDE + i] = sm[SLEN + i];
    }
}

// ---------------------------------------------------------------------------
// K5b: chunked partial-slice reduce (input stride parameterized)
// ---------------------------------------------------------------------------
__global__ __launch_bounds__(256) void reduce_part_kernel(
    const float* __restrict__ part, int P, int csz, int instride,
    float* __restrict__ out)
{
    int j = blockIdx.x * 256 + threadIdx.x;
    if (j >= SLEN) return;
    int p0 = blockIdx.y * csz;
    int p1 = min(P, p0 + csz);
    float a = 0.f;
    for (int p = p0; p < p1; ++p) a += part[(size_t)p * instride + j];
    out[(size_t)blockIdx.y * PSTRIDE + j] = a;
}

// ---------------------------------------------------------------------------
// K6: stats -> packed scale/bias tables + packed LN table + fused bias
// ---------------------------------------------------------------------------
__global__ __launch_bounds__(256) void finstats_kernel(
    const float* __restrict__ statsH, const float* __restrict__ statsE,
    const float* __restrict__ gnh_ms, const float* __restrict__ gne_ms,
    const float* __restrict__ gnh_w, const float* __restrict__ gnh_b,
    const float* __restrict__ gne_w, const float* __restrict__ gne_b,
    const float* __restrict__ ln_w, const float* __restrict__ ln_b,
    const float* __restrict__ be, const float* __restrict__ bo,
    float* __restrict__ SBh, float* __restrict__ SBe,
    float* __restrict__ LNWB, float* __restrict__ bsum)
{
    const int t = threadIdx.x;
    if (t < 64) {
        LNWB[4 * t]     = ln_w[2 * t];
        LNWB[4 * t + 1] = ln_b[2 * t];
        LNWB[4 * t + 2] = ln_w[2 * t + 1];
        LNWB[4 * t + 3] = ln_b[2 * t + 1];
    }
    if (t >= 64 && t < 192) bsum[t - 64] = be[t - 64] + bo[t - 64];
    for (int i = t; i < GG * HD; i += 256) {
        int g = i >> 7, c = i & 127;
        {
            float cnt = fmaxf(statsH[4096 + g], 1.f);
            float mean = statsH[i] / cnt;
            float ex2 = statsH[2048 + i] / cnt;
            float off = mean * gnh_ms[c];
            float var = ex2 - 2.f * off * mean + off * off;
            float S = gnh_w[c] * rsqrtf(var + EPSV);
            SBh[2 * i]     = S;
            SBh[2 * i + 1] = gnh_b[c] - off * S;
        }
        {
            float cnt = fmaxf(statsE[4096 + g], 1.f);
            float mean = statsE[i] / cnt;
            float ex2 = statsE[2048 + i] / cnt;
            float off = mean * gne_ms[c];
            float var = ex2 - 2.f * off * mean + off * off;
            float S = gne_w[c] * rsqrtf(var + EPSV);
            SBe[2 * i]     = S;
            SBe[2 * i + 1] = gne_b[c] - off * S;
        }
    }
}

// ---------------------------------------------------------------------------
// K7: tproj = relu(time_emb) @ Wt + bt   [16 x 128]
// ---------------------------------------------------------------------------
__global__ __launch_bounds__(256) void tproj_kernel(
    const float* __restrict__ time_emb, const float* __restrict__ Wt,
    const float* __restrict__ bt, float* __restrict__ tproj)
{
    __shared__ float te[GG][HD];
    const int t = threadIdx.x;
    for (int i = t; i < GG * HD; i += 256) te[i >> 7][i & 127] = fmaxf(time_emb[i], 0.f);
    __syncthreads();
    const int c = t & 127, rb = t >> 7;
    float acc[8];
    #pragma unroll
    for (int j = 0; j < 8; ++j) acc[j] = 0.f;
    for (int k = 0; k < HD; ++k) {
        float wv = Wt[k * HD + c];
        #pragma unroll
        for (int j = 0; j < 8; ++j) acc[j] = fmaf(te[rb + 2 * j][k], wv, acc[j]);
    }
    float b = bt[c];
    #pragma unroll
    for (int j = 0; j < 8; ++j) tproj[(rb + 2 * j) * HD + c] = acc[j] + b;
}

// ---------------------------------------------------------------------------
// K8: h = features + max(S*x+B, 0);  x lives in hout (in-place)
// ---------------------------------------------------------------------------
__global__ __launch_bounds__(256) void hfinal_kernel(
    const float* __restrict__ feat, const int* __restrict__ batch,
    const float* __restrict__ SBh, float* hout_x)
{
    int i = blockIdx.x * 256 + threadIdx.x;
    size_t base = (size_t)i * 4;
    if (base >= (size_t)NN * HD) return;
    int row = (int)(base >> 7), c0 = (int)(base & 127);
    int g = batch[row];
    float4 fe = *reinterpret_cast<const float4*>(&feat[base]);
    float4 xv = *reinterpret_cast<const float4*>(&hout_x[base]);
    float4 sb0 = *reinterpret_cast<const float4*>(&SBh[(size_t)(g * HD + c0) * 2]);
    float4 sb1 = *reinterpret_cast<const float4*>(&SBh[(size_t)(g * HD + c0 + 2) * 2]);
    float4 ou;
    ou.x = fe.x + fmaxf(fmaf(xv.x, sb0.x, sb0.y), 0.f);
    ou.y = fe.y + fmaxf(fmaf(xv.y, sb0.z, sb0.w), 0.f);
    ou.z = fe.z + fmaxf(fmaf(xv.z, sb1.x, sb1.y), 0.f);
    ou.w = fe.w + fmaxf(fmaf(xv.w, sb1.z, sb1.w), 0.f);
    *reinterpret_cast<float4*>(&hout_x[base]) = ou;
}

// ---------------------------------------------------------------------------
// K9 (FUSED eprep+GEMM, CSR order), register-dieted phase 1:
//   pass A: accumulate s1=Σa, s2=Σa² only (moment-form variance)
//   reduce; pass B: re-read ehat row (L1-hot), recompute a, LN+silu -> aw
//   eout[perm[j]] = a@WoT + noise[perm[j]]@WeT + (be+bo)
// ---------------------------------------------------------------------------
__global__ __launch_bounds__(512) void efinal_kernel(
    const u16* __restrict__ ehat_csr, const u8* __restrict__ g8csr,
    const float* __restrict__ noise, const int* __restrict__ perm,
    const u16* __restrict__ WoT, const u16* __restrict__ WeT,
    const float* __restrict__ bsum, const float* __restrict__ SBe,
    const float* __restrict__ tproj, const float* __restrict__ LNWB,
    float* __restrict__ eout)
{
    __shared__ __align__(16) u16 WoL[2048 * 8];   // 32 KB, fragment order
    __shared__ __align__(16) u16 WeL[1024 * 8];   // 16 KB, fragment order
    const int t = threadIdx.x;
    #pragma unroll
    for (int q = 0; q < 4; ++q) {
        int f = t + q * 512;
        int fl15 = f & 15, kgi = (f >> 4) & 15, fnt = f >> 8;
        *reinterpret_cast<uint4*>(&WoL[f * 8]) =
            *reinterpret_cast<const uint4*>(&WoT[(size_t)(fnt * 16 + fl15) * HD + kgi * 8]);
    }
    #pragma unroll
    for (int q = 0; q < 2; ++q) {
        int f = t + q * 512;
        int fl15 = f & 15, kgi = (f >> 4) & 7, fnt = f >> 7;
        *reinterpret_cast<uint4*>(&WeL[f * 8]) =
            *reinterpret_cast<const uint4*>(&WeT[(size_t)(fnt * 16 + fl15) * ND + kgi * 8]);
    }

    const int rbase = blockIdx.x * 128;
    const int w = t >> 6, lane = t & 63;
    const int l15 = lane & 15, kg = lane >> 4;
    const int rt = w * 16;
    const int jl = rbase + rt + l15;       // this lane's CSR row (A-frag row)
    const int g = g8csr[jl];
    const int el = perm[jl];               // original edge id (noise row)

    // pass A: moments only (no per-element state kept)
    float s1 = 0.f, s2 = 0.f;
    #pragma unroll
    for (int kk = 0; kk < 4; ++kk) {
        const int c = kk * 32 + kg * 8;
        uint4 ev = *reinterpret_cast<const uint4*>(&ehat_csr[(size_t)jl * HD + c]);
        const u32 wds[4] = {ev.x, ev.y, ev.z, ev.w};
        #pragma unroll
        for (int p = 0; p < 4; ++p) {
            const int c2 = c + p * 2;
            float x0 = us2f((u16)wds[p]);
            float x1 = us2f((u16)(wds[p] >> 16));
            float4 sb = *reinterpret_cast<const float4*>(&SBe[(size_t)(g * HD + c2) * 2]);
            float2 tp = *reinterpret_cast<const float2*>(&tproj[g * HD + c2]);
            float a0 = fmaxf(fmaf(x0, sb.x, sb.y), 0.f) + tp.x;
            float a1 = fmaxf(fmaf(x1, sb.z, sb.w), 0.f) + tp.y;
            s1 += a0 + a1;
            s2 = fmaf(a0, a0, fmaf(a1, a1, s2));
        }
    }
    s1 += __shfl_xor(s1, 16, 64);
    s1 += __shfl_xor(s1, 32, 64);
    s2 += __shfl_xor(s2, 16, 64);
    s2 += __shfl_xor(s2, 32, 64);
    float mu = s1 * (1.f / 128.f);
    float var = s2 * (1.f / 128.f) - mu * mu;
    float rstd = rsqrtf(var + EPSV);

    // pass B: re-read (L1-hot), recompute a, LN+silu -> bf16 A-fragments
    u32 aw[4][4];
    #pragma unroll
    for (int kk = 0; kk < 4; ++kk) {
        const int c = kk * 32 + kg * 8;
        uint4 ev = *reinterpret_cast<const uint4*>(&ehat_csr[(size_t)jl * HD + c]);
        const u32 wds[4] = {ev.x, ev.y, ev.z, ev.w};
        #pragma unroll
        for (int p = 0; p < 4; ++p) {
            const int c2 = c + p * 2;
            float x0 = us2f((u16)wds[p]);
            float x1 = us2f((u16)(wds[p] >> 16));
            float4 sb = *reinterpret_cast<const float4*>(&SBe[(size_t)(g * HD + c2) * 2]);
            float2 tp = *reinterpret_cast<const float2*>(&tproj[g * HD + c2]);
            float a0 = fmaxf(fmaf(x0, sb.x, sb.y), 0.f) + tp.x;
            float a1 = fmaxf(fmaf(x1, sb.z, sb.w), 0.f) + tp.y;
            float4 lnwb = *reinterpret_cast<const float4*>(&LNWB[(kk * 16 + kg * 4 + p) * 4]);
            float l0 = (a0 - mu) * rstd * lnwb.x + lnwb.y;
            float l1 = (a1 - mu) * rstd * lnwb.z + lnwb.w;
            float si0 = l0 * sigmoidf_(l0);
            float si1 = l1 * sigmoidf_(l1);
            aw[kk][p] = (u32)f2us(si0) | ((u32)f2us(si1) << 16);
        }
    }
    // noise A-fragments (f32 -> bf16 in-register)
    u32 an[2][4];
    #pragma unroll
    for (int kk = 0; kk < 2; ++kk) {
        const int c = kk * 32 + kg * 8;
        float4 n0 = *reinterpret_cast<const float4*>(&noise[(size_t)el * ND + c]);
        float4 n1 = *reinterpret_cast<const float4*>(&noise[(size_t)el * ND + c + 4]);
        an[kk][0] = (u32)f2us(n0.x) | ((u32)f2us(n0.y) << 16);
        an[kk][1] = (u32)f2us(n0.z) | ((u32)f2us(n0.w) << 16);
        an[kk][2] = (u32)f2us(n1.x) | ((u32)f2us(n1.y) << 16);
        an[kk][3] = (u32)f2us(n1.z) | ((u32)f2us(n1.w) << 16);
    }
    int prow[4];
    #pragma unroll
    for (int i = 0; i < 4; ++i) prow[i] = perm[rbase + rt + kg * 4 + i];
    __syncthreads();

    // phase 2: MFMA from LDS fragment-order weights
    f32x4 acc[8];
    #pragma unroll
    for (int nt = 0; nt < 8; ++nt) {
        float bs = bsum[nt * 16 + l15];
        acc[nt][0] = bs; acc[nt][1] = bs; acc[nt][2] = bs; acc[nt][3] = bs;
    }
    const int lid = kg * 16 + l15;
    #pragma unroll
    for (int nt = 0; nt < 8; ++nt) {
        #pragma unroll
        for (int kk = 0; kk < 4; ++kk) {
            bf16x8 b = *reinterpret_cast<const bf16x8*>(&WoL[(((nt * 4 + kk) * 64) + lid) * 8]);
            acc[nt] = __builtin_amdgcn_mfma_f32_16x16x32_bf16(
                *reinterpret_cast<const bf16x8*>(aw[kk]), b, acc[nt], 0, 0, 0);
        }
        #pragma unroll
        for (int kk = 0; kk < 2; ++kk) {
            bf16x8 b = *reinterpret_cast<const bf16x8*>(&WeL[(((nt * 2 + kk) * 64) + lid) * 8]);
            acc[nt] = __builtin_amdgcn_mfma_f32_16x16x32_bf16(
                *reinterpret_cast<const bf16x8*>(an[kk]), b, acc[nt], 0, 0, 0);
        }
    }
    #pragma unroll
    for (int nt = 0; nt < 8; ++nt) {
        int gcol = nt * 16 + l15;
        #pragma unroll
        for (int i = 0; i < 4; ++i) {
            eout[(size_t)prow[i] * HD + gcol] = acc[nt][i];
        }
    }
}

// ---------------------------------------------------------------------------
extern "C" void kernel_launch(void* const* d_in, const int* in_sizes, int n_in,
                              void* d_out, int out_size, void* d_ws, size_t ws_size,
                              hipStream_t stream)
{
    const float* feat     = (const float*)d_in[0];
    const int*   eidx     = (const int*)d_in[1];
    const float* noise    = (const float*)d_in[2];
    const float* time_emb = (const float*)d_in[3];
    const int*   batch    = (const int*)d_in[4];
    const float* We = (const float*)d_in[5],  *be = (const float*)d_in[6];
    const float* Wp = (const float*)d_in[7],  *bp = (const float*)d_in[8];
    const float* Wq = (const float*)d_in[9],  *bq = (const float*)d_in[10];
    const float* Wr = (const float*)d_in[11], *br = (const float*)d_in[12];
    const float* Wu = (const float*)d_in[13], *bu = (const float*)d_in[14];
    const float* Wv = (const float*)d_in[15], *bv = (const float*)d_in[16];
    const float* gnh_w = (const float*)d_in[17], *gnh_b = (const float*)d_in[18], *gnh_ms = (const float*)d_in[19];
    const float* gne_w = (const float*)d_in[20], *gne_b = (const float*)d_in[21], *gne_ms = (const float*)d_in[22];
    const float* Wt = (const float*)d_in[23], *bt = (const float*)d_in[24];
    const float* ln_w = (const float*)d_in[25], *ln_b = (const float*)d_in[26];
    const float* Wo = (const float*)d_in[27], *bo = (const float*)d_in[28];

    const int* srcArr = eidx;
    const int* dstArr = eidx + NE;

    float* hout = (float*)d_out;                    // [N,H] f32 — holds fu32, then x, then h
    float* eout = hout + (size_t)NN * HD;           // [E,H] f32 — final e

    char* ws = (char*)d_ws;
    size_t off = 0;
    auto take = [&](size_t bytes) -> char* {
        char* p = ws + off;
        off = (off + bytes + 255) & ~(size_t)255;
        return p;
    };
    u16* ehat = (u16*)take((size_t)NE * HD * 2);    // 102.4 MB (CSR order, raw)
    u16* fq = (u16*)take((size_t)NN * HD * 2);      // 12.8 MB
    u16* fr = (u16*)take((size_t)NN * HD * 2);
    u16* fv = (u16*)take((size_t)NN * HD * 2);
    u8*  g8csr = (u8*)take((size_t)NE);
    u32* deg  = (u32*)take((size_t)2 * NN * 4);     // deg[NN] + cnt2[NN], one memset
    u32* cnt2 = deg + NN;
    int* start = (int*)take((size_t)(NN + 1) * 4);
    int* perm  = (int*)take((size_t)NE * 4);
    int* iperm = (int*)take((size_t)NE * 4);        // 1.6 MB
    int* dst_csr = (int*)take((size_t)NE * 4);      // 1.6 MB
    float* Wep = (float*)take((size_t)ND * HD * 4);
    float* bep = (float*)take((size_t)HD * 4);
    u16* WqT = (u16*)take((size_t)HD * HD * 2);     // transposed bf16 weights
    u16* WrT = (u16*)take((size_t)HD * HD * 2);
    u16* WvT = (u16*)take((size_t)HD * HD * 2);
    u16* WuT = (u16*)take((size_t)HD * HD * 2);
    u16* WoT = (u16*)take((size_t)HD * HD * 2);
    u16* WepT = (u16*)take((size_t)HD * ND * 2);
    u16* WeT  = (u16*)take((size_t)HD * ND * 2);
    float* statsH = (float*)take((size_t)PSTRIDE * 4);
    float* statsE = (float*)take((size_t)PSTRIDE * 4);
    float* tproj  = (float*)take((size_t)GG * HD * 4);
    float* SBh    = (float*)take((size_t)GG * HD * 8);   // {S,B} interleaved
    float* SBe    = (float*)take((size_t)GG * HD * 8);
    float* LNWB   = (float*)take((size_t)64 * 4 * 4);    // {lw,lb} pairs
    float* bsum   = (float*)take((size_t)HD * 4);        // be+bo
    float* part   = (float*)take((size_t)ASB * 2 * PSTRIDE * 4);  // 17.8 MB fused stats
    float* etmp   = (float*)take((size_t)8 * PSTRIDE * 4);
    float* htmp   = (float*)take((size_t)8 * PSTRIDE * 4);
    // total ~165.1 MB — under the ~167.77 MB budget (R3 pass / R4 fail bound)

    hipMemsetAsync(deg, 0, (size_t)2 * NN * 4, stream);

    wep_kernel<<<16, 256, 0, stream>>>(We, Wp, be, bp, Wep, bep);
    prep_all_kernel<<<dim3(64, 7), 256, 0, stream>>>(Wq, Wr, Wv, Wu, Wo, Wep, We,
                                                     WqT, WrT, WvT, WuT, WoT, WepT, WeT);
    hist_kernel<<<(NE + 255) / 256, 256, 0, stream>>>(srcArr, deg);
    scan_kernel<<<1, 1024, 0, stream>>>(deg, start);
    scatter_kernel<<<(NE + 255) / 256, 256, 0, stream>>>(srcArr, dstArr, batch, start,
                                                         cnt2, perm, iperm,
                                                         dst_csr, g8csr);
    proj4_kernel<<<(NN + ETILE - 1) / ETILE, 256, 0, stream>>>(
        feat, WqT, WrT, WvT, WuT, bq, br, bv, bu, fq, fr, fv, hout);
    ehat_kernel<<<NE / ETILE, 256, 0, stream>>>(noise, WepT, bep, fq, fr,
                                                srcArr, dstArr, iperm, ehat);
    aggr_stats_kernel<<<ASB, 512, 0, stream>>>(ehat, fv, dst_csr, start, batch, hout, part);
    {
        dim3 gA((SLEN + 255) / 256, 8);
        reduce_part_kernel<<<gA, 256, 0, stream>>>(part, ASB, ASB / 8, 2 * PSTRIDE, etmp);
        reduce_part_kernel<<<gA, 256, 0, stream>>>(part + PSTRIDE, ASB, ASB / 8, 2 * PSTRIDE, htmp);
        dim3 gB((SLEN + 255) / 256, 1);
        reduce_part_kernel<<<gB, 256, 0, stream>>>(etmp, 8, 8, PSTRIDE, statsE);
        reduce_part_kernel<<<gB, 256, 0, stream>>>(htmp, 8, 8, PSTRIDE, statsH);
    }
    tproj_kernel<<<1, 256, 0, stream>>>(time_emb, Wt, bt, tproj);
    finstats_kernel<<<1, 256, 0, stream>>>(statsH, statsE, gnh_ms, gne_ms,
                                           gnh_w, gnh_b, gne_w, gne_b,
                                           ln_w, ln_b, be, bo,
                                           SBh, SBe, LNWB, bsum);
    hfinal_kernel<<<(NN * HD / 4 + 255) / 256, 256, 0, stream>>>(feat, batch, SBh, hout);
    efinal_kernel<<<NE / 128, 512, 0, stream>>>(ehat, g8csr, noise, perm, WoT, WeT,
                                                bsum, SBe, tproj, LNWB, eout);
}

// Round 20
// 639.186 us; speedup vs baseline: 1.0288x; 1.0288x over previous
//
#include <hip/hip_runtime.h>

#define NN 50000
#define NE 400000
#define HD 128
#define ND 64
#define GG 16
#define EPSV 1e-5f
#define ETILE 64

#define SLEN (2 * GG * HD + GG)   // 4112 floats: [sum 2048 | sumsq 2048 | cnt 16]
#define PSTRIDE 4352              // partial-set stride (floats), non-pow2
#define ASB 512                   // fused aggr+stats blocks (8 waves each)

typedef unsigned short u16;
typedef unsigned int   u32;
typedef unsigned char  u8;
typedef __attribute__((__ext_vector_type__(8))) __bf16 bf16x8;
typedef __attribute__((__ext_vector_type__(4))) float  f32x4;

__device__ __forceinline__ float us2f(u16 u) { return __uint_as_float(((u32)u) << 16); }
__device__ __forceinline__ u16 f2us(float f) {
    u32 u = __float_as_uint(f);
    u += 0x7fffu + ((u >> 16) & 1u);   // RNE
    return (u16)(u >> 16);
}
__device__ __forceinline__ float sigmoidf_(float x) { return 1.f / (1.f + __expf(-x)); }

// ---------------------------------------------------------------------------
// K0a: Wep = We @ Wp  [64x128], bep = be @ Wp + bp   (grid=16, Wp in LDS)
// ---------------------------------------------------------------------------
__global__ __launch_bounds__(256) void wep_kernel(
    const float* __restrict__ We, const float* __restrict__ Wp,
    const float* __restrict__ be, const float* __restrict__ bp,
    float* __restrict__ Wep, float* __restrict__ bep)
{
    __shared__ float wp[HD][HD];      // 64 KB
    const int t = threadIdx.x;
    for (int i = t; i < HD * HD; i += 256) wp[i >> 7][i & 127] = Wp[i];
    __syncthreads();
    const int c = t & 127;
    for (int r = blockIdx.x * 4 + (t >> 7); r < (blockIdx.x + 1) * 4 && r < ND; r += 2) {
        float a = 0.f;
        for (int k = 0; k < HD; ++k) a = fmaf(We[r * HD + k], wp[k][c], a);
        Wep[r * HD + c] = a;
    }
    if (blockIdx.x == 0 && t < HD) {
        float a = bp[t];
        for (int k = 0; k < HD; ++k) a = fmaf(be[k], wp[k][t], a);
        bep[t] = a;
    }
}

// ---------------------------------------------------------------------------
// K0e: all weight transposes in ONE launch. grid=(64,7).
// ---------------------------------------------------------------------------
__global__ __launch_bounds__(256) void prep_all_kernel(
    const float* __restrict__ Wq, const float* __restrict__ Wr,
    const float* __restrict__ Wv, const float* __restrict__ Wu,
    const float* __restrict__ Wo, const float* __restrict__ Wep,
    const float* __restrict__ We,
    u16* __restrict__ WqT, u16* __restrict__ WrT, u16* __restrict__ WvT,
    u16* __restrict__ WuT, u16* __restrict__ WoT, u16* __restrict__ WepT,
    u16* __restrict__ WeT)
{
    const float* in; u16* out; int K;
    switch (blockIdx.y) {
        case 0: in = Wq;  out = WqT;  K = HD; break;
        case 1: in = Wr;  out = WrT;  K = HD; break;
        case 2: in = Wv;  out = WvT;  K = HD; break;
        case 3: in = Wu;  out = WuT;  K = HD; break;
        case 4: in = Wo;  out = WoT;  K = HD; break;
        case 5: in = Wep; out = WepT; K = ND; break;
        default: in = We; out = WeT;  K = ND; break;
    }
    int idx = blockIdx.x * 256 + threadIdx.x;
    if (idx >= K * HD) return;
    int k = idx >> 7, n = idx & 127;
    out[n * K + k] = f2us(in[idx]);
}

// ---------------------------------------------------------------------------
// K0b: degree histogram
// ---------------------------------------------------------------------------
__global__ __launch_bounds__(256) void hist_kernel(
    const int* __restrict__ srcArr, u32* __restrict__ deg)
{
    int e = blockIdx.x * 256 + threadIdx.x;
    if (e >= NE) return;
    atomicAdd(&deg[srcArr[e]], 1u);
}

// ---------------------------------------------------------------------------
// K0c: exclusive prefix sum of deg[NN] -> start[NN+1]   (1 block, 1024 thr)
// ---------------------------------------------------------------------------
#define SCAN_C 49   // 1024*49 = 50176 >= NN
__global__ __launch_bounds__(1024) void scan_kernel(
    const u32* __restrict__ deg, int* __restrict__ start)
{
    __shared__ u32 sums[1024];
    const int t = threadIdx.x;
    const int i0 = t * SCAN_C;
    u32 tot = 0;
    for (int j = 0; j < SCAN_C; ++j) { int i = i0 + j; if (i < NN) tot += deg[i]; }
    sums[t] = tot;
    __syncthreads();
    for (int off = 1; off < 1024; off <<= 1) {
        u32 v = (t >= off) ? sums[t - off] : 0u;
        __syncthreads();
        sums[t] += v;
        __syncthreads();
    }
    u32 run = (t == 0) ? 0u : sums[t - 1];
    for (int j = 0; j < SCAN_C; ++j) {
        int i = i0 + j;
        if (i < NN) { start[i] = (int)run; run += deg[i]; }
    }
    if (t == 1023) start[NN] = (int)run;   // == NE
}

// ---------------------------------------------------------------------------
// K0d: scatter edges into CSR order + dst/g8 in CSR order + iperm[e] = j
// ---------------------------------------------------------------------------
__global__ __launch_bounds__(256) void scatter_kernel(
    const int* __restrict__ srcArr, const int* __restrict__ dstArr,
    const int* __restrict__ batch, const int* __restrict__ start,
    u32* __restrict__ cnt2, int* __restrict__ perm,
    int* __restrict__ iperm, int* __restrict__ dst_csr,
    u8* __restrict__ g8csr)
{
    int e = blockIdx.x * 256 + threadIdx.x;
    if (e >= NE) return;
    int s = srcArr[e];
    u32 pos = atomicAdd(&cnt2[s], 1u);
    int j = start[s] + (int)pos;
    perm[j] = e;
    iperm[e] = j;
    dst_csr[j] = dstArr[e];
    g8csr[j] = (u8)batch[s];
}

// ---------------------------------------------------------------------------
// K1: MFMA: fq/fr/fv = feat @ {Wq,Wr,Wv} + b (bf16); fu32 = feat@Wu + bu (f32)
//     Weights staged per-matrix in LDS fragment order (32 KB).
// ---------------------------------------------------------------------------
__global__ __launch_bounds__(256) void proj4_kernel(
    const float* __restrict__ feat,
    const u16* __restrict__ WqT, const u16* __restrict__ WrT,
    const u16* __restrict__ WvT, const u16* __restrict__ WuT,
    const float* __restrict__ bq, const float* __restrict__ br,
    const float* __restrict__ bv, const float* __restrict__ bu,
    u16* __restrict__ fq, u16* __restrict__ fr, u16* __restrict__ fv,
    float* __restrict__ fu32)
{
    __shared__ __align__(16) u16 As[ETILE * HD];   // 16 KB, XOR-swizzled
    __shared__ __align__(16) u16 WL[2048 * 8];     // 32 KB, fragment order
    const int t = threadIdx.x;
    const int rbase = blockIdx.x * ETILE;
    #pragma unroll
    for (int i = 0; i < 16; ++i) {
        int idx2 = t + i * 256;            // bf16-pair index
        int row = idx2 >> 6, p = idx2 & 63;
        int grow = rbase + row;
        float2 v = make_float2(0.f, 0.f);
        if (grow < NN) v = *reinterpret_cast<const float2*>(&feat[(size_t)grow * HD + p * 2]);
        u32 pk = (u32)f2us(v.x) | ((u32)f2us(v.y) << 16);
        int off = (row * 256 + p * 4) ^ ((row & 7) << 4);
        *reinterpret_cast<u32*>(reinterpret_cast<char*>(As) + off) = pk;
    }
    __syncthreads();
    const int w = t >> 6, lane = t & 63;
    const int rt = w * 16, l15 = lane & 15, kg = lane >> 4;
    const int lrow = rt + l15;
    bf16x8 afr[4];
    #pragma unroll
    for (int kk = 0; kk < 4; ++kk) {
        int off = (lrow * 256 + (kk * 32 + kg * 8) * 2) ^ ((lrow & 7) << 4);
        afr[kk] = *reinterpret_cast<const bf16x8*>(reinterpret_cast<const char*>(As) + off);
    }
    const u16* WTs[4] = {WqT, WrT, WvT, WuT};
    const float* Bs2[4] = {bq, br, bv, bu};
    u16* Os[3] = {fq, fr, fv};
    const int lid = kg * 16 + l15;
    #pragma unroll
    for (int m = 0; m < 4; ++m) {
        const u16* W = WTs[m];
        #pragma unroll
        for (int q = 0; q < 8; ++q) {
            int f = t + q * 256;
            int fl15 = f & 15, kgi = (f >> 4) & 15, fnt = f >> 8;
            *reinterpret_cast<uint4*>(&WL[f * 8]) =
                *reinterpret_cast<const uint4*>(&W[(size_t)(fnt * 16 + fl15) * HD + kgi * 8]);
        }
        __syncthreads();
        f32x4 acc[8];
        #pragma unroll
        for (int nt = 0; nt < 8; ++nt) { acc[nt][0]=0.f; acc[nt][1]=0.f; acc[nt][2]=0.f; acc[nt][3]=0.f; }
        #pragma unroll
        for (int nt = 0; nt < 8; ++nt) {
            #pragma unroll
            for (int kk = 0; kk < 4; ++kk) {
                bf16x8 b = *reinterpret_cast<const bf16x8*>(&WL[(((nt * 4 + kk) * 64) + lid) * 8]);
                acc[nt] = __builtin_amdgcn_mfma_f32_16x16x32_bf16(afr[kk], b, acc[nt], 0, 0, 0);
            }
        }
        #pragma unroll
        for (int nt = 0; nt < 8; ++nt) {
            int gcol = nt * 16 + l15;
            float bias = Bs2[m][gcol];
            #pragma unroll
            for (int i = 0; i < 4; ++i) {
                int grow = rbase + rt + kg * 4 + i;
                if (grow < NN) {
                    float v = acc[nt][i] + bias;
                    if (m < 3) Os[m][(size_t)grow * HD + gcol] = f2us(v);
                    else       fu32[(size_t)grow * HD + gcol] = v;
                }
            }
        }
        __syncthreads();   // all reads of WL done before next-stage overwrite
    }
}

// ---------------------------------------------------------------------------
// K3: MFMA in ORIGINAL edge order: for edge e,
//   ehat_csr[iperm[e]] = noise[e]@Wep + bep + fq[srcArr[e]] + fr[dstArr[e]]
// ---------------------------------------------------------------------------
__global__ __launch_bounds__(256) void ehat_kernel(
    const float* __restrict__ noise, const u16* __restrict__ WepT,
    const float* __restrict__ bep,
    const u16* __restrict__ fq, const u16* __restrict__ fr,
    const int* __restrict__ srcArr, const int* __restrict__ dstArr,
    const int* __restrict__ iperm,
    u16* __restrict__ ehat_csr)
{
    __shared__ __align__(16) u16 WeL[1024 * 8];   // 16 KB, fragment order
    const int t = threadIdx.x;
    #pragma unroll
    for (int q = 0; q < 4; ++q) {
        int f = t + q * 256;
        int fl15 = f & 15, kgi = (f >> 4) & 7, fnt = f >> 7;
        *reinterpret_cast<uint4*>(&WeL[f * 8]) =
            *reinterpret_cast<const uint4*>(&WepT[(size_t)(fnt * 16 + fl15) * ND + kgi * 8]);
    }
    const int rbase = blockIdx.x * ETILE;
    const int w = t >> 6, lane = t & 63;
    const int rt = w * 16, l15 = lane & 15, kg = lane >> 4;
    const int el = rbase + rt + l15;      // original edge (A-frag row) — coalesced
    u32 an[2][4];
    #pragma unroll
    for (int kk = 0; kk < 2; ++kk) {
        const int c = kk * 32 + kg * 8;
        float4 n0 = *reinterpret_cast<const float4*>(&noise[(size_t)el * ND + c]);
        float4 n1 = *reinterpret_cast<const float4*>(&noise[(size_t)el * ND + c + 4]);
        an[kk][0] = (u32)f2us(n0.x) | ((u32)f2us(n0.y) << 16);
        an[kk][1] = (u32)f2us(n0.z) | ((u32)f2us(n0.w) << 16);
        an[kk][2] = (u32)f2us(n1.x) | ((u32)f2us(n1.y) << 16);
        an[kk][3] = (u32)f2us(n1.z) | ((u32)f2us(n1.w) << 16);
    }
    __syncthreads();
    f32x4 acc[8];
    #pragma unroll
    for (int nt = 0; nt < 8; ++nt) {
        float b = bep[nt * 16 + l15];
        acc[nt][0] = b; acc[nt][1] = b; acc[nt][2] = b; acc[nt][3] = b;
    }
    const int lid = kg * 16 + l15;
    #pragma unroll
    for (int nt = 0; nt < 8; ++nt) {
        #pragma unroll
        for (int kk = 0; kk < 2; ++kk) {
            bf16x8 b = *reinterpret_cast<const bf16x8*>(&WeL[(((nt * 2 + kk) * 64) + lid) * 8]);
            acc[nt] = __builtin_amdgcn_mfma_f32_16x16x32_bf16(
                *reinterpret_cast<const bf16x8*>(an[kk]), b, acc[nt], 0, 0, 0);
        }
    }
    #pragma unroll
    for (int i = 0; i < 4; ++i) {
        int e = rbase + rt + kg * 4 + i;
        int s = srcArr[e], d = dstArr[e];
        int j = iperm[e];
        #pragma unroll
        for (int nt = 0; nt < 8; ++nt) {
            int gcol = nt * 16 + l15;
            float v = acc[nt][i]
                    + us2f(fq[(size_t)s * HD + gcol]) + us2f(fr[(size_t)d * HD + gcol]);
            ehat_csr[(size_t)j * HD + gcol] = f2us(v);
        }
    }
}

// ---------------------------------------------------------------------------
// K3b (FUSED): one CSR-sequential pass computing aggregation + e/h stats
// ---------------------------------------------------------------------------
__global__ __launch_bounds__(512) void aggr_stats_kernel(
    const u16* __restrict__ ehat_csr, const u16* __restrict__ fv,
    const int* __restrict__ dst_csr, const int* __restrict__ start,
    const int* __restrict__ batch, float* __restrict__ xout,
    float* __restrict__ part)
{
    __shared__ float sm[2 * SLEN];   // 32.9 KB: [e: sum|sumsq|cnt][h: sum|sumsq|cnt]
    const int t = threadIdx.x;
    for (int i = t; i < 2 * SLEN; i += 512) sm[i] = 0.f;
    __syncthreads();
    const int wid = blockIdx.x * 8 + (t >> 6);
    const int lane = t & 63;
    const int c0 = lane * 2;
    const int NW = ASB * 8;
    const int chunk = (NN + NW - 1) / NW;
    const int n0 = wid * chunk;
    const int n1 = min(NN, n0 + chunk);
    const float inc = (lane == 0) ? 1.f : 0.f;
    float es0=0.f, es1=0.f, ez0=0.f, ez1=0.f, ecn=0.f;
    float hs0=0.f, hs1=0.f, hz0=0.f, hz1=0.f, hcn=0.f;
    int curg = -1;
    for (int node = n0; node < n1; ++node) {
        int g = __builtin_amdgcn_readfirstlane(batch[node]);
        if (g != curg) {
            if (curg >= 0) {
                unsafeAtomicAdd(&sm[curg * HD + c0],            es0);
                unsafeAtomicAdd(&sm[curg * HD + c0 + 1],        es1);
                unsafeAtomicAdd(&sm[2048 + curg * HD + c0],     ez0);
                unsafeAtomicAdd(&sm[2048 + curg * HD + c0 + 1], ez1);
                unsafeAtomicAdd(&sm[SLEN + curg * HD + c0],            hs0);
                unsafeAtomicAdd(&sm[SLEN + curg * HD + c0 + 1],        hs1);
                unsafeAtomicAdd(&sm[SLEN + 2048 + curg * HD + c0],     hz0);
                unsafeAtomicAdd(&sm[SLEN + 2048 + curg * HD + c0 + 1], hz1);
                if (lane == 0) {
                    unsafeAtomicAdd(&sm[4096 + curg], ecn);
                    unsafeAtomicAdd(&sm[SLEN + 4096 + curg], hcn);
                }
                es0=0.f; es1=0.f; ez0=0.f; ez1=0.f; ecn=0.f;
                hs0=0.f; hs1=0.f; hz0=0.f; hz1=0.f; hcn=0.f;
            }
            curg = g;
        }
        int s0 = start[node], s1 = start[node + 1];
        float2 uv = *reinterpret_cast<const float2*>(&xout[(size_t)node * HD + c0]);
        float a0 = 0.f, a1 = 0.f;
        for (int j = s0; j < s1; ++j) {
            int d = dst_csr[j];
            u32 ev = *reinterpret_cast<const u32*>(&ehat_csr[(size_t)j * HD + c0]);
            u32 vv = *reinterpret_cast<const u32*>(&fv[(size_t)d * HD + c0]);
            float x0 = us2f((u16)ev), x1 = us2f((u16)(ev >> 16));
            a0 = fmaf(sigmoidf_(x0), us2f((u16)vv),         a0);
            a1 = fmaf(sigmoidf_(x1), us2f((u16)(vv >> 16)), a1);
            es0 += x0; ez0 = fmaf(x0, x0, ez0);
            es1 += x1; ez1 = fmaf(x1, x1, ez1);
            ecn += inc;
        }
        float xx0 = a0 + uv.x, xx1 = a1 + uv.y;
        *reinterpret_cast<float2*>(&xout[(size_t)node * HD + c0]) = make_float2(xx0, xx1);
        hs0 += xx0; hz0 = fmaf(xx0, xx0, hz0);
        hs1 += xx1; hz1 = fmaf(xx1, xx1, hz1);
        hcn += inc;
    }
    if (curg >= 0) {
        unsafeAtomicAdd(&sm[curg * HD + c0],            es0);
        unsafeAtomicAdd(&sm[curg * HD + c0 + 1],        es1);
        unsafeAtomicAdd(&sm[2048 + curg * HD + c0],     ez0);
        unsafeAtomicAdd(&sm[2048 + curg * HD + c0 + 1], ez1);
        unsafeAtomicAdd(&sm[SLEN + curg * HD + c0],            hs0);
        unsafeAtomicAdd(&sm[SLEN + curg * HD + c0 + 1],        hs1);
        unsafeAtomicAdd(&sm[SLEN + 2048 + curg * HD + c0],     hz0);
        unsafeAtomicAdd(&sm[SLEN + 2048 + curg * HD + c0 + 1], hz1);
        if (lane == 0) {
            unsafeAtomicAdd(&sm[4096 + curg], ecn);
            unsafeAtomicAdd(&sm[SLEN + 4096 + curg], hcn);
        }
    }
    __syncthreads();
    float* dst = part + (size_t)blockIdx.x * (2 * PSTRIDE);
    for (int i = t; i < SLEN; i += 512) {
        dst[i] = sm[i];
        dst[PSTRIDE + i] = sm[SLEN + i];
    }
}

// ---------------------------------------------------------------------------
// K5b: chunked partial-slice reduce (input stride parameterized)
// ---------------------------------------------------------------------------
__global__ __launch_bounds__(256) void reduce_part_kernel(
    const float* __restrict__ part, int P, int csz, int instride,
    float* __restrict__ out)
{
    int j = blockIdx.x * 256 + threadIdx.x;
    if (j >= SLEN) return;
    int p0 = blockIdx.y * csz;
    int p1 = min(P, p0 + csz);
    float a = 0.f;
    for (int p = p0; p < p1; ++p) a += part[(size_t)p * instride + j];
    out[(size_t)blockIdx.y * PSTRIDE + j] = a;
}

// ---------------------------------------------------------------------------
// K6: stats -> packed scale/bias tables + packed LN table + fused bias
// ---------------------------------------------------------------------------
__global__ __launch_bounds__(256) void finstats_kernel(
    const float* __restrict__ statsH, const float* __restrict__ statsE,
    const float* __restrict__ gnh_ms, const float* __restrict__ gne_ms,
    const float* __restrict__ gnh_w, const float* __restrict__ gnh_b,
    const float* __restrict__ gne_w, const float* __restrict__ gne_b,
    const float* __restrict__ ln_w, const float* __restrict__ ln_b,
    const float* __restrict__ be, const float* __restrict__ bo,
    float* __restrict__ SBh, float* __restrict__ SBe,
    float* __restrict__ LNWB, float* __restrict__ bsum)
{
    const int t = threadIdx.x;
    if (t < 64) {
        LNWB[4 * t]     = ln_w[2 * t];
        LNWB[4 * t + 1] = ln_b[2 * t];
        LNWB[4 * t + 2] = ln_w[2 * t + 1];
        LNWB[4 * t + 3] = ln_b[2 * t + 1];
    }
    if (t >= 64 && t < 192) bsum[t - 64] = be[t - 64] + bo[t - 64];
    for (int i = t; i < GG * HD; i += 256) {
        int g = i >> 7, c = i & 127;
        {
            float cnt = fmaxf(statsH[4096 + g], 1.f);
            float mean = statsH[i] / cnt;
            float ex2 = statsH[2048 + i] / cnt;
            float off = mean * gnh_ms[c];
            float var = ex2 - 2.f * off * mean + off * off;
            float S = gnh_w[c] * rsqrtf(var + EPSV);
            SBh[2 * i]     = S;
            SBh[2 * i + 1] = gnh_b[c] - off * S;
        }
        {
            float cnt = fmaxf(statsE[4096 + g], 1.f);
            float mean = statsE[i] / cnt;
            float ex2 = statsE[2048 + i] / cnt;
            float off = mean * gne_ms[c];
            float var = ex2 - 2.f * off * mean + off * off;
            float S = gne_w[c] * rsqrtf(var + EPSV);
            SBe[2 * i]     = S;
            SBe[2 * i + 1] = gne_b[c] - off * S;
        }
    }
}

// ---------------------------------------------------------------------------
// K7: tproj = relu(time_emb) @ Wt + bt   [16 x 128]
// ---------------------------------------------------------------------------
__global__ __launch_bounds__(256) void tproj_kernel(
    const float* __restrict__ time_emb, const float* __restrict__ Wt,
    const float* __restrict__ bt, float* __restrict__ tproj)
{
    __shared__ float te[GG][HD];
    const int t = threadIdx.x;
    for (int i = t; i < GG * HD; i += 256) te[i >> 7][i & 127] = fmaxf(time_emb[i], 0.f);
    __syncthreads();
    const int c = t & 127, rb = t >> 7;
    float acc[8];
    #pragma unroll
    for (int j = 0; j < 8; ++j) acc[j] = 0.f;
    for (int k = 0; k < HD; ++k) {
        float wv = Wt[k * HD + c];
        #pragma unroll
        for (int j = 0; j < 8; ++j) acc[j] = fmaf(te[rb + 2 * j][k], wv, acc[j]);
    }
    float b = bt[c];
    #pragma unroll
    for (int j = 0; j < 8; ++j) tproj[(rb + 2 * j) * HD + c] = acc[j] + b;
}

// ---------------------------------------------------------------------------
// K8: h = features + max(S*x+B, 0);  x lives in hout (in-place)
// ---------------------------------------------------------------------------
__global__ __launch_bounds__(256) void hfinal_kernel(
    const float* __restrict__ feat, const int* __restrict__ batch,
    const float* __restrict__ SBh, float* hout_x)
{
    int i = blockIdx.x * 256 + threadIdx.x;
    size_t base = (size_t)i * 4;
    if (base >= (size_t)NN * HD) return;
    int row = (int)(base >> 7), c0 = (int)(base & 127);
    int g = batch[row];
    float4 fe = *reinterpret_cast<const float4*>(&feat[base]);
    float4 xv = *reinterpret_cast<const float4*>(&hout_x[base]);
    float4 sb0 = *reinterpret_cast<const float4*>(&SBh[(size_t)(g * HD + c0) * 2]);
    float4 sb1 = *reinterpret_cast<const float4*>(&SBh[(size_t)(g * HD + c0 + 2) * 2]);
    float4 ou;
    ou.x = fe.x + fmaxf(fmaf(xv.x, sb0.x, sb0.y), 0.f);
    ou.y = fe.y + fmaxf(fmaf(xv.y, sb0.z, sb0.w), 0.f);
    ou.z = fe.z + fmaxf(fmaf(xv.z, sb1.x, sb1.y), 0.f);
    ou.w = fe.w + fmaxf(fmaf(xv.w, sb1.z, sb1.w), 0.f);
    *reinterpret_cast<float4*>(&hout_x[base]) = ou;
}

// ---------------------------------------------------------------------------
// K9 (FUSED eprep+GEMM, CSR order): per CSR row j:
//   a = silu(LN(max(S*ehat[j]+B,0) + tproj[g]))  — in registers, row-LN via
//       2 shfl_xor across the 4 lanes sharing the row
//   eout[perm[j]] = a@WoT + noise[perm[j]]@WeT + (be+bo)
//   Weights staged in LDS in fragment order. ehat never rewritten.
// ---------------------------------------------------------------------------
__global__ __launch_bounds__(512) void efinal_kernel(
    const u16* __restrict__ ehat_csr, const u8* __restrict__ g8csr,
    const float* __restrict__ noise, const int* __restrict__ perm,
    const u16* __restrict__ WoT, const u16* __restrict__ WeT,
    const float* __restrict__ bsum, const float* __restrict__ SBe,
    const float* __restrict__ tproj, const float* __restrict__ LNWB,
    float* __restrict__ eout)
{
    __shared__ __align__(16) u16 WoL[2048 * 8];   // 32 KB, fragment order
    __shared__ __align__(16) u16 WeL[1024 * 8];   // 16 KB, fragment order
    const int t = threadIdx.x;
    #pragma unroll
    for (int q = 0; q < 4; ++q) {
        int f = t + q * 512;
        int fl15 = f & 15, kgi = (f >> 4) & 15, fnt = f >> 8;
        *reinterpret_cast<uint4*>(&WoL[f * 8]) =
            *reinterpret_cast<const uint4*>(&WoT[(size_t)(fnt * 16 + fl15) * HD + kgi * 8]);
    }
    #pragma unroll
    for (int q = 0; q < 2; ++q) {
        int f = t + q * 512;
        int fl15 = f & 15, kgi = (f >> 4) & 7, fnt = f >> 7;
        *reinterpret_cast<uint4*>(&WeL[f * 8]) =
            *reinterpret_cast<const uint4*>(&WeT[(size_t)(fnt * 16 + fl15) * ND + kgi * 8]);
    }

    const int rbase = blockIdx.x * 128;
    const int w = t >> 6, lane = t & 63;
    const int l15 = lane & 15, kg = lane >> 4;
    const int rt = w * 16;
    const int jl = rbase + rt + l15;       // this lane's CSR row (A-frag row)
    const int g = g8csr[jl];
    const int el = perm[jl];               // original edge id (noise row)

    // phase 1: GN+tproj+LN+silu for this lane's 32 fragment cols
    float v[4][8];
    float lsum = 0.f;
    #pragma unroll
    for (int kk = 0; kk < 4; ++kk) {
        const int c = kk * 32 + kg * 8;
        uint4 ev = *reinterpret_cast<const uint4*>(&ehat_csr[(size_t)jl * HD + c]);
        const u32 wds[4] = {ev.x, ev.y, ev.z, ev.w};
        #pragma unroll
        for (int p = 0; p < 4; ++p) {
            const int c2 = c + p * 2;
            float x0 = us2f((u16)wds[p]);
            float x1 = us2f((u16)(wds[p] >> 16));
            float4 sb = *reinterpret_cast<const float4*>(&SBe[(size_t)(g * HD + c2) * 2]);
            float2 tp = *reinterpret_cast<const float2*>(&tproj[g * HD + c2]);
            float a0 = fmaxf(fmaf(x0, sb.x, sb.y), 0.f) + tp.x;
            float a1 = fmaxf(fmaf(x1, sb.z, sb.w), 0.f) + tp.y;
            v[kk][p * 2]     = a0;
            v[kk][p * 2 + 1] = a1;
            lsum += a0 + a1;
        }
    }
    lsum += __shfl_xor(lsum, 16, 64);
    lsum += __shfl_xor(lsum, 32, 64);
    float mu = lsum * (1.f / 128.f);
    float sq = 0.f;
    #pragma unroll
    for (int kk = 0; kk < 4; ++kk)
        #pragma unroll
        for (int j = 0; j < 8; ++j) { float d = v[kk][j] - mu; sq = fmaf(d, d, sq); }
    sq += __shfl_xor(sq, 16, 64);
    sq += __shfl_xor(sq, 32, 64);
    float rstd = rsqrtf(sq * (1.f / 128.f) + EPSV);
    u32 aw[4][4];
    #pragma unroll
    for (int kk = 0; kk < 4; ++kk) {
        #pragma unroll
        for (int p = 0; p < 4; ++p) {
            float4 lnwb = *reinterpret_cast<const float4*>(&LNWB[(kk * 16 + kg * 4 + p) * 4]);
            float l0 = (v[kk][p * 2]     - mu) * rstd * lnwb.x + lnwb.y;
            float l1 = (v[kk][p * 2 + 1] - mu) * rstd * lnwb.z + lnwb.w;
            float s0 = l0 * sigmoidf_(l0);
            float s1 = l1 * sigmoidf_(l1);
            aw[kk][p] = (u32)f2us(s0) | ((u32)f2us(s1) << 16);
        }
    }
    // noise A-fragments (f32 -> bf16 in-register)
    u32 an[2][4];
    #pragma unroll
    for (int kk = 0; kk < 2; ++kk) {
        const int c = kk * 32 + kg * 8;
        float4 n0 = *reinterpret_cast<const float4*>(&noise[(size_t)el * ND + c]);
        float4 n1 = *reinterpret_cast<const float4*>(&noise[(size_t)el * ND + c + 4]);
        an[kk][0] = (u32)f2us(n0.x) | ((u32)f2us(n0.y) << 16);
        an[kk][1] = (u32)f2us(n0.z) | ((u32)f2us(n0.w) << 16);
        an[kk][2] = (u32)f2us(n1.x) | ((u32)f2us(n1.y) << 16);
        an[kk][3] = (u32)f2us(n1.z) | ((u32)f2us(n1.w) << 16);
    }
    int prow[4];
    #pragma unroll
    for (int i = 0; i < 4; ++i) prow[i] = perm[rbase + rt + kg * 4 + i];
    __syncthreads();

    // phase 2: MFMA from LDS fragment-order weights
    f32x4 acc[8];
    #pragma unroll
    for (int nt = 0; nt < 8; ++nt) {
        float bs = bsum[nt * 16 + l15];
        acc[nt][0] = bs; acc[nt][1] = bs; acc[nt][2] = bs; acc[nt][3] = bs;
    }
    const int lid = kg * 16 + l15;
    #pragma unroll
    for (int nt = 0; nt < 8; ++nt) {
        #pragma unroll
        for (int kk = 0; kk < 4; ++kk) {
            bf16x8 b = *reinterpret_cast<const bf16x8*>(&WoL[(((nt * 4 + kk) * 64) + lid) * 8]);
            acc[nt] = __builtin_amdgcn_mfma_f32_16x16x32_bf16(
                *reinterpret_cast<const bf16x8*>(aw[kk]), b, acc[nt], 0, 0, 0);
        }
        #pragma unroll
        for (int kk = 0; kk < 2; ++kk) {
            bf16x8 b = *reinterpret_cast<const bf16x8*>(&WeL[(((nt * 2 + kk) * 64) + lid) * 8]);
            acc[nt] = __builtin_amdgcn_mfma_f32_16x16x32_bf16(
                *reinterpret_cast<const bf16x8*>(an[kk]), b, acc[nt], 0, 0, 0);
        }
    }
    #pragma unroll
    for (int nt = 0; nt < 8; ++nt) {
        int gcol = nt * 16 + l15;
        #pragma unroll
        for (int i = 0; i < 4; ++i) {
            eout[(size_t)prow[i] * HD + gcol] = acc[nt][i];
        }
    }
}

// ---------------------------------------------------------------------------
extern "C" void kernel_launch(void* const* d_in, const int* in_sizes, int n_in,
                              void* d_out, int out_size, void* d_ws, size_t ws_size,
                              hipStream_t stream)
{
    const float* feat     = (const float*)d_in[0];
    const int*   eidx     = (const int*)d_in[1];
    const float* noise    = (const float*)d_in[2];
    const float* time_emb = (const float*)d_in[3];
    const int*   batch    = (const int*)d_in[4];
    const float* We = (const float*)d_in[5],  *be = (const float*)d_in[6];
    const float* Wp = (const float*)d_in[7],  *bp = (const float*)d_in[8];
    const float* Wq = (const float*)d_in[9],  *bq = (const float*)d_in[10];
    const float* Wr = (const float*)d_in[11], *br = (const float*)d_in[12];
    const float* Wu = (const float*)d_in[13], *bu = (const float*)d_in[14];
    const float* Wv = (const float*)d_in[15], *bv = (const float*)d_in[16];
    const float* gnh_w = (const float*)d_in[17], *gnh_b = (const float*)d_in[18], *gnh_ms = (const float*)d_in[19];
    const float* gne_w = (const float*)d_in[20], *gne_b = (const float*)d_in[21], *gne_ms = (const float*)d_in[22];
    const float* Wt = (const float*)d_in[23], *bt = (const float*)d_in[24];
    const float* ln_w = (const float*)d_in[25], *ln_b = (const float*)d_in[26];
    const float* Wo = (const float*)d_in[27], *bo = (const float*)d_in[28];

    const int* srcArr = eidx;
    const int* dstArr = eidx + NE;

    float* hout = (float*)d_out;                    // [N,H] f32 — holds fu32, then x, then h
    float* eout = hout + (size_t)NN * HD;           // [E,H] f32 — final e

    char* ws = (char*)d_ws;
    size_t off = 0;
    auto take = [&](size_t bytes) -> char* {
        char* p = ws + off;
        off = (off + bytes + 255) & ~(size_t)255;
        return p;
    };
    u16* ehat = (u16*)take((size_t)NE * HD * 2);    // 102.4 MB (CSR order, raw)
    u16* fq = (u16*)take((size_t)NN * HD * 2);      // 12.8 MB
    u16* fr = (u16*)take((size_t)NN * HD * 2);
    u16* fv = (u16*)take((size_t)NN * HD * 2);
    u8*  g8csr = (u8*)take((size_t)NE);
    u32* deg  = (u32*)take((size_t)2 * NN * 4);     // deg[NN] + cnt2[NN], one memset
    u32* cnt2 = deg + NN;
    int* start = (int*)take((size_t)(NN + 1) * 4);
    int* perm  = (int*)take((size_t)NE * 4);
    int* iperm = (int*)take((size_t)NE * 4);        // 1.6 MB
    int* dst_csr = (int*)take((size_t)NE * 4);      // 1.6 MB
    float* Wep = (float*)take((size_t)ND * HD * 4);
    float* bep = (float*)take((size_t)HD * 4);
    u16* WqT = (u16*)take((size_t)HD * HD * 2);     // transposed bf16 weights
    u16* WrT = (u16*)take((size_t)HD * HD * 2);
    u16* WvT = (u16*)take((size_t)HD * HD * 2);
    u16* WuT = (u16*)take((size_t)HD * HD * 2);
    u16* WoT = (u16*)take((size_t)HD * HD * 2);
    u16* WepT = (u16*)take((size_t)HD * ND * 2);
    u16* WeT  = (u16*)take((size_t)HD * ND * 2);
    float* statsH = (float*)take((size_t)PSTRIDE * 4);
    float* statsE = (float*)take((size_t)PSTRIDE * 4);
    float* tproj  = (float*)take((size_t)GG * HD * 4);
    float* SBh    = (float*)take((size_t)GG * HD * 8);   // {S,B} interleaved
    float* SBe    = (float*)take((size_t)GG * HD * 8);
    float* LNWB   = (float*)take((size_t)64 * 4 * 4);    // {lw,lb} pairs
    float* bsum   = (float*)take((size_t)HD * 4);        // be+bo
    float* part   = (float*)take((size_t)ASB * 2 * PSTRIDE * 4);  // 17.8 MB fused stats
    float* etmp   = (float*)take((size_t)8 * PSTRIDE * 4);
    float* htmp   = (float*)take((size_t)8 * PSTRIDE * 4);
    // total ~165.1 MB — under the ~167.77 MB budget (R3 pass / R4 fail bound)

    hipMemsetAsync(deg, 0, (size_t)2 * NN * 4, stream);

    wep_kernel<<<16, 256, 0, stream>>>(We, Wp, be, bp, Wep, bep);
    prep_all_kernel<<<dim3(64, 7), 256, 0, stream>>>(Wq, Wr, Wv, Wu, Wo, Wep, We,
                                                     WqT, WrT, WvT, WuT, WoT, WepT, WeT);
    hist_kernel<<<(NE + 255) / 256, 256, 0, stream>>>(srcArr, deg);
    scan_kernel<<<1, 1024, 0, stream>>>(deg, start);
    scatter_kernel<<<(NE + 255) / 256, 256, 0, stream>>>(srcArr, dstArr, batch, start,
                                                         cnt2, perm, iperm,
                                                         dst_csr, g8csr);
    proj4_kernel<<<(NN + ETILE - 1) / ETILE, 256, 0, stream>>>(
        feat, WqT, WrT, WvT, WuT, bq, br, bv, bu, fq, fr, fv, hout);
    ehat_kernel<<<NE / ETILE, 256, 0, stream>>>(noise, WepT, bep, fq, fr,
                                                srcArr, dstArr, iperm, ehat);
    aggr_stats_kernel<<<ASB, 512, 0, stream>>>(ehat, fv, dst_csr, start, batch, hout, part);
    {
        dim3 gA((SLEN + 255) / 256, 8);
        reduce_part_kernel<<<gA, 256, 0, stream>>>(part, ASB, ASB / 8, 2 * PSTRIDE, etmp);
        reduce_part_kernel<<<gA, 256, 0, stream>>>(part + PSTRIDE, ASB, ASB / 8, 2 * PSTRIDE, htmp);
        dim3 gB((SLEN + 255) / 256, 1);
        reduce_part_kernel<<<gB, 256, 0, stream>>>(etmp, 8, 8, PSTRIDE, statsE);
        reduce_part_kernel<<<gB, 256, 0, stream>>>(htmp, 8, 8, PSTRIDE, statsH);
    }
    tproj_kernel<<<1, 256, 0, stream>>>(time_emb, Wt, bt, tproj);
    finstats_kernel<<<1, 256, 0, stream>>>(statsH, statsE, gnh_ms, gne_ms,
                                           gnh_w, gnh_b, gne_w, gne_b,
                                           ln_w, ln_b, be, bo,
                                           SBh, SBe, LNWB, bsum);
    hfinal_kernel<<<(NN * HD / 4 + 255) / 256, 256, 0, stream>>>(feat, batch, SBh, hout);
    efinal_kernel<<<NE / 128, 512, 0, stream>>>(ehat, g8csr, noise, perm, WoT, WeT,
                                                bsum, SBe, tproj, LNWB, eout);
}